// Round 9
// baseline (204.841 us; speedup 1.0000x reference)
//
#include <hip/hip_runtime.h>
#include <stdint.h>

// BinConv2d: sign(x) conv3x3(pad1) sign(w) + batch-stat BN.
// Conv as int8 implicit GEMM on MFMA (v_mfma_i32_32x32x32_i8), integer-exact.
// R9: wave = 32px x 128oc (ds:MFMA = 1:4), acc 64 regs (3 waves/SIMD), swapped
// operands (A=weights) for contiguous stores, stats as separate y16 pass.

#define HH 56
#define WW 56
#define CC 128
#define OO 128
#define NIMG 64
#define PIX (HH*WW)               // 3136
#define CNT (NIMG*PIX)            // 200704 per channel
#define TOT ((size_t)NIMG*OO*PIX) // 25690112

typedef int v4i  __attribute__((ext_vector_type(4)));
typedef int v16i __attribute__((ext_vector_type(16)));

// ws layout (bytes)
#define WS_WBT   0                 // 9*8*128*16 int8 (wbt2[tap][kc][o][16]) = 147456
#define WS_STATS 147456            // 128*{i64 sum, i64 sq} = 2048
#define WS_SS    149504            // float2[128] = 1024
#define WS_XI8   151552            // NHWC int8 sign(x): 64*3136*128 -> ends 25841664
#define WS_Y16   25841664          // TOT*int16 = 51380224 -> ends 77221888
#define WS_NEED  (25841664ULL + (size_t)TOT * 2)

// wbt2[tap][kc][o] x 16B: k-outer so B-fragment loads are lane-consecutive 16B.
__global__ void pack_w_i8(const float* __restrict__ w, char* __restrict__ wbt) {
    int t = blockIdx.x * 256 + threadIdx.x;
    if (t >= 1152) return;
    int tap = t >> 7, o = t & 127;
    const float* wp = w + (size_t)o * (CC * 9) + tap;   // OIHW: + c*9
    #pragma unroll
    for (int kc = 0; kc < 8; ++kc) {
        v4i v;
        #pragma unroll
        for (int wd = 0; wd < 4; ++wd) {
            unsigned u = 0;
            #pragma unroll
            for (int b = 0; b < 4; ++b) {
                int c = kc * 16 + wd * 4 + b;
                float f = wp[c * 9];
                int s = (f > 0.f) - (f < 0.f);
                u |= (unsigned)((unsigned char)(char)s) << (8 * b);
            }
            v[wd] = (int)u;
        }
        *(v4i*)(wbt + (((size_t)tap * 8 + kc) * 128 + o) * 16) = v;
    }
}

// xi8[n][h][w][c] int8 (NHWC, c contiguous = MFMA K dim)
__global__ void pack_x_i8(const float* __restrict__ x, char* __restrict__ xi8) {
    int n = blockIdx.y;
    int p = blockIdx.x * 256 + threadIdx.x;
    if (p >= PIX) return;
    const float* xp = x + (size_t)n * CC * PIX + p;
    char* dst = xi8 + ((size_t)n * PIX + p) * CC;
    #pragma unroll
    for (int chunk = 0; chunk < 8; ++chunk) {
        v4i v;
        #pragma unroll
        for (int wd = 0; wd < 4; ++wd) {
            unsigned u = 0;
            #pragma unroll
            for (int b = 0; b < 4; ++b) {
                int c = chunk * 16 + wd * 4 + b;
                float f = xp[(size_t)c * PIX];
                int s = (f > 0.f) - (f < 0.f);
                u |= (unsigned)((unsigned char)(char)s) << (8 * b);
            }
            v[wd] = (int)u;
        }
        *(v4i*)(dst + chunk * 16) = v;
    }
}

// MODE 1: y16 out. MODE 2: raw float y to out (fallback path, stats read from out).
// Block 256 = 4 waves; wave = 32 consecutive pixels x ALL 128 oc; strip = 128 px.
// A-tile: 6 image rows x 58 cols, k-outer [kc][p] 16B units in LDS (conflict-free).
// MFMA operands: A = weights (M=32 oc), B = activations (N=32 px) -> D row=oc, col=px.
template <int MODE>
__global__ __launch_bounds__(256, 2) void conv_mfma(
    const char* __restrict__ xi8, const char* __restrict__ wbt,
    short* __restrict__ y16, float* __restrict__ out)
{
    __shared__ __align__(16) char Atile[8 * 348 * 16];   // 44544 B

    const int strip = blockIdx.x;   // 0..24 (128 px each; last has 64 valid)
    const int n = blockIdx.y;
    const int tid = threadIdx.x;
    const int lane = tid & 63;
    const int wave = tid >> 6;
    const int ln31 = lane & 31;
    const int kbase = lane >> 5;    // k half (0/1)
    const int p0 = strip * 128;
    const int r0 = p0 / 56 - 1;     // first tile image-row (may be -1)

    // ---- stage A: tile[kc][pr][pc] = xi8[n][r0+pr][pc-1][kc*16..+16) or 0
    {
        const char* xim = xi8 + (size_t)n * PIX * CC;
        for (int idx = tid; idx < 8 * 348; idx += 256) {
            int kc = idx / 348, p = idx - kc * 348;
            int pr = p / 58, pc = p - pr * 58;
            int gr = r0 + pr, gw = pc - 1;
            v4i v = {0, 0, 0, 0};
            if (gr >= 0 && gr < HH && gw >= 0 && gw < WW)
                v = *(const v4i*)(xim + ((size_t)(gr * WW + gw)) * CC + kc * 16);
            *(v4i*)(Atile + idx * 16) = v;
        }
    }

    // my pixel (B-operand column): q = p0 + wave*32 + ln31 (may be >= PIX on last strip)
    const int q = p0 + wave * 32 + ln31;
    const int qr = q / 56;
    const int hl0 = qr - (r0 + 1);            // 0..3
    const int ww = q - qr * 56;
    const int xpb = (hl0 * 58 + ww) * 16;     // + (dr*58+dc)*16 + kc*5568

    const char* bw = wbt + (kbase * 128 + ln31) * 16;   // + tap*16384 + ks*4096 + nt*512

    v16i acc[4];
    #pragma unroll
    for (int nt = 0; nt < 4; ++nt) {
        #pragma unroll
        for (int i = 0; i < 16; ++i) acc[nt][i] = 0;
    }

    __syncthreads();

    const char* bptr = bw;
    #pragma unroll 1
    for (int dr = 0; dr < 3; ++dr) {
        #pragma unroll 1
        for (int dc = 0; dc < 3; ++dc) {
            v4i wf[4][4];   // weights frag [ks][nt]
            #pragma unroll
            for (int ks = 0; ks < 4; ++ks)
                #pragma unroll
                for (int nt = 0; nt < 4; ++nt)
                    wf[ks][nt] = *(const v4i*)(bptr + ks * 4096 + nt * 512);
            const char* ap = Atile + xpb + (dr * 58 + dc) * 16;
            v4i xf[4];
            #pragma unroll
            for (int ks = 0; ks < 4; ++ks)
                xf[ks] = *(const v4i*)(ap + (ks * 2 + kbase) * 5568);
            #pragma unroll
            for (int ks = 0; ks < 4; ++ks)
                #pragma unroll
                for (int nt = 0; nt < 4; ++nt)
                    acc[nt] = __builtin_amdgcn_mfma_i32_32x32x32_i8(
                        wf[ks][nt], xf[ks], acc[nt], 0, 0, 0);
            bptr += 16384;
        }
    }

    // ---- epilogue: D row = oc = nt*32 + (r&3)+8*(r>>2)+4*kbase, col = pixel (ln31)
    const bool valid = (p0 + wave * 32) < PIX;   // wave-uniform (last strip waves 2,3 invalid)
    if (!valid) return;
    const int px = p0 + wave * 32 + ln31;
    if (MODE == 1) {
        #pragma unroll
        for (int nt = 0; nt < 4; ++nt) {
            size_t obase = ((size_t)n * OO + nt * 32 + kbase * 4) * PIX + px;
            #pragma unroll
            for (int r = 0; r < 16; ++r) {
                int o_off = (r & 3) + 8 * (r >> 2);
                y16[obase + (size_t)o_off * PIX] = (short)acc[nt][r];
            }
        }
    } else {
        #pragma unroll
        for (int nt = 0; nt < 4; ++nt) {
            size_t obase = ((size_t)n * OO + nt * 32 + kbase * 4) * PIX + px;
            #pragma unroll
            for (int r = 0; r < 16; ++r) {
                int o_off = (r & 3) + 8 * (r >> 2);
                out[obase + (size_t)o_off * PIX] = (float)acc[nt][r];
            }
        }
    }
}

// per-(n,o) row stats from y16; grid (128 o, 64 n)
__global__ __launch_bounds__(256) void stats16_kernel(const short* __restrict__ y16,
                                                      unsigned long long* __restrict__ stats) {
    const int o = blockIdx.x, n = blockIdx.y;
    const int tid = threadIdx.x;
    const short* row = y16 + ((size_t)n * OO + o) * PIX;
    int sum = 0, sq = 0;   // <=16 el/thread: |sum|<=18K, sq<=21.3M (i32-safe)
    for (int c = tid; c < PIX * 2 / 16; c += 256) {   // 392 16B chunks
        int4 raw = *(const int4*)(row + c * 8);
        #pragma unroll
        for (int wdi = 0; wdi < 4; ++wdi) {
            int u = (&raw.x)[wdi];
            int lo = (int)(short)(u & 0xffff);
            int hi = (int)(short)(u >> 16);
            sum += lo + hi;
            sq += lo * lo + hi * hi;
        }
    }
    // wave reduce (wave-level sq <= 1024*1152^2 = 1.36e9 < 2^31)
    #pragma unroll
    for (int off = 32; off; off >>= 1) {
        sum += __shfl_down(sum, off);
        sq  += __shfl_down(sq, off);
    }
    __shared__ long long wsum[4], wsq[4];
    if ((tid & 63) == 0) { wsum[tid >> 6] = sum; wsq[tid >> 6] = sq; }
    __syncthreads();
    if (tid == 0) {
        long long ts = wsum[0] + wsum[1] + wsum[2] + wsum[3];
        long long tq = wsq[0] + wsq[1] + wsq[2] + wsq[3];
        atomicAdd(&stats[o * 2 + 0], (unsigned long long)ts);
        atomicAdd(&stats[o * 2 + 1], (unsigned long long)tq);
    }
}

// fallback: stats from raw float y stored in out
__global__ __launch_bounds__(256) void statsf_kernel(const float* __restrict__ yf,
                                                     unsigned long long* __restrict__ stats) {
    const int o = blockIdx.x, n = blockIdx.y;
    const int tid = threadIdx.x;
    const float* row = yf + ((size_t)n * OO + o) * PIX;
    int sum = 0, sq = 0;
    for (int c = tid; c < PIX / 4; c += 256) {   // 784 float4 chunks
        float4 raw = *(const float4*)(row + c * 4);
        int a = (int)raw.x, b = (int)raw.y, cc2 = (int)raw.z, d = (int)raw.w;
        sum += a + b + cc2 + d;
        sq += a * a + b * b + cc2 * cc2 + d * d;
    }
    #pragma unroll
    for (int off = 32; off; off >>= 1) {
        sum += __shfl_down(sum, off);
        sq  += __shfl_down(sq, off);
    }
    __shared__ long long wsum[4], wsq[4];
    if ((tid & 63) == 0) { wsum[tid >> 6] = sum; wsq[tid >> 6] = sq; }
    __syncthreads();
    if (tid == 0) {
        long long ts = wsum[0] + wsum[1] + wsum[2] + wsum[3];
        long long tq = wsq[0] + wsq[1] + wsq[2] + wsq[3];
        atomicAdd(&stats[o * 2 + 0], (unsigned long long)ts);
        atomicAdd(&stats[o * 2 + 1], (unsigned long long)tq);
    }
}

__global__ void finalize_kernel(const unsigned long long* __restrict__ stats,
                                const float* __restrict__ gamma,
                                const float* __restrict__ beta,
                                float2* __restrict__ ss) {
    int c = threadIdx.x;
    if (c >= 128) return;
    long long s = (long long)stats[c * 2 + 0];
    long long q = (long long)stats[c * 2 + 1];
    double mean = (double)s / (double)CNT;
    double var = (double)q / (double)CNT - mean * mean;
    double inv = 1.0 / sqrt(var + 1e-5);
    double g = (double)gamma[c];
    float sc = (float)(g * inv);
    float sh = (float)((double)beta[c] - mean * g * inv);
    ss[c] = make_float2(sc, sh);
}

// 8 elements/thread; 3136 % 8 == 0 so a group never crosses a channel boundary.
__global__ void norm_kernel(const short* __restrict__ y16,
                            const float2* __restrict__ ss,
                            float* __restrict__ out) {
    size_t g = (size_t)blockIdx.x * 256 + threadIdx.x;
    size_t e = g * 8;
    unsigned int chan = (unsigned int)((e / PIX) & 127);
    float2 v = ss[chan];
    int4 raw = *reinterpret_cast<const int4*>(y16 + e);
    float4 o0, o1;
    o0.x = (float)(short)(raw.x & 0xffff) * v.x + v.y;
    o0.y = (float)(short)(raw.x >> 16)    * v.x + v.y;
    o0.z = (float)(short)(raw.y & 0xffff) * v.x + v.y;
    o0.w = (float)(short)(raw.y >> 16)    * v.x + v.y;
    o1.x = (float)(short)(raw.z & 0xffff) * v.x + v.y;
    o1.y = (float)(short)(raw.z >> 16)    * v.x + v.y;
    o1.z = (float)(short)(raw.w & 0xffff) * v.x + v.y;
    o1.w = (float)(short)(raw.w >> 16)    * v.x + v.y;
    *reinterpret_cast<float4*>(out + e) = o0;
    *reinterpret_cast<float4*>(out + e + 4) = o1;
}

// fallback: in-place normalize of raw float y in out
__global__ void normf_kernel(float* __restrict__ out, const float2* __restrict__ ss) {
    size_t g = (size_t)blockIdx.x * 256 + threadIdx.x;
    size_t e = g * 8;
    unsigned int chan = (unsigned int)((e / PIX) & 127);
    float2 v = ss[chan];
    float4 a = *reinterpret_cast<const float4*>(out + e);
    float4 b = *reinterpret_cast<const float4*>(out + e + 4);
    a.x = a.x * v.x + v.y; a.y = a.y * v.x + v.y; a.z = a.z * v.x + v.y; a.w = a.w * v.x + v.y;
    b.x = b.x * v.x + v.y; b.y = b.y * v.x + v.y; b.z = b.z * v.x + v.y; b.w = b.w * v.x + v.y;
    *reinterpret_cast<float4*>(out + e) = a;
    *reinterpret_cast<float4*>(out + e + 4) = b;
}

extern "C" void kernel_launch(void* const* d_in, const int* in_sizes, int n_in,
                              void* d_out, int out_size, void* d_ws, size_t ws_size,
                              hipStream_t stream) {
    const float* x     = (const float*)d_in[0];
    const float* wgt   = (const float*)d_in[1];
    const float* gamma = (const float*)d_in[2];
    const float* beta  = (const float*)d_in[3];
    float* out = (float*)d_out;
    char* ws = (char*)d_ws;

    char* wbt = ws + WS_WBT;
    unsigned long long* stats = (unsigned long long*)(ws + WS_STATS);
    float2* ssp = (float2*)(ws + WS_SS);
    char* xi8 = ws + WS_XI8;
    short* y16 = (short*)(ws + WS_Y16);

    hipMemsetAsync(stats, 0, 2048, stream);
    pack_w_i8<<<5, 256, 0, stream>>>(wgt, wbt);
    pack_x_i8<<<dim3(13, 64), 256, 0, stream>>>(x, xi8);

    if (ws_size >= WS_NEED) {
        conv_mfma<1><<<dim3(25, 64), 256, 0, stream>>>(xi8, wbt, y16, nullptr);
        stats16_kernel<<<dim3(128, 64), 256, 0, stream>>>(y16, stats);
        finalize_kernel<<<1, 128, 0, stream>>>(stats, gamma, beta, ssp);
        norm_kernel<<<(unsigned)(TOT / 8 / 256), 256, 0, stream>>>(y16, ssp, out);
    } else {
        conv_mfma<2><<<dim3(25, 64), 256, 0, stream>>>(xi8, wbt, nullptr, out);
        statsf_kernel<<<dim3(128, 64), 256, 0, stream>>>(out, stats);
        finalize_kernel<<<1, 128, 0, stream>>>(stats, gamma, beta, ssp);
        normf_kernel<<<(unsigned)(TOT / 8 / 256), 256, 0, stream>>>(out, ssp);
    }
}